// Round 1
// baseline (395.258 us; speedup 1.0000x reference)
//
#include <hip/hip_runtime.h>
#include <math.h>

// Problem constants (B,L,H,E,M) = (4,4096,8,64,64)
#define Bsz 4
#define Lsz 4096
#define Hsz 8
#define Esz 64
#define Msz 64
#define HEsz 512     // H*E
#define CCsz 128     // 2*M interleaved (re,im)
#define ROWS 2048    // B*H*E

// workspace layout in floats (total 1,572,864 floats = 6 MiB)
#define OFF_BASF 0                               // [L][CC]  forward basis, l-major
#define OFF_BASI (Lsz*CCsz)                      // [CC][L]  inverse basis, k-major
#define OFF_C1   (2*Lsz*CCsz)                    // [B][HE][CC] forward DFT output
#define OFF_CF   (2*Lsz*CCsz + Bsz*HEsz*CCsz)    // [ROWS][CC] mixed+scaled coeffs

static __device__ __forceinline__ float2 twiddle(int m, int l) {
    // exact mod since L = 4096: angle = 2*pi*((m*l) mod L)/L, arg in [0, 2pi)
    int r = (m * l) & (Lsz - 1);
    float ang = (float)r * (6.283185307179586f / (float)Lsz);
    float s, c;
    __sincosf(ang, &s, &c);
    return make_float2(c, s);
}

// forward basis: basF[l*128 + 2m] = cos, basF[l*128 + 2m+1] = -sin  (rfft: e^{-i t})
__global__ __launch_bounds__(256) void k_tableF(float* __restrict__ ws) {
    int tid = blockIdx.x * 256 + threadIdx.x;   // 524288
    int l = tid >> 7, c = tid & 127;
    int m = c >> 1;
    float2 cs = twiddle(m, l);
    ws[OFF_BASF + tid] = (c & 1) ? -cs.y : cs.x;
}

// inverse basis: basI[(2m)*4096 + l] = cos, basI[(2m+1)*4096 + l] = sin
__global__ __launch_bounds__(256) void k_tableI(float* __restrict__ ws) {
    int tid = blockIdx.x * 256 + threadIdx.x;   // 524288
    int k = tid >> 12, l = tid & 4095;
    int m = k >> 1;
    float2 cs = twiddle(m, l);
    ws[OFF_BASI + tid] = (k & 1) ? cs.y : cs.x;
}

// zero C1 region (ws is re-poisoned 0xAA before every launch)
__global__ __launch_bounds__(256) void k_zero(float* __restrict__ ws) {
    int tid = blockIdx.x * 256 + threadIdx.x;   // 65536, one float4 each
    ((float4*)(ws + OFF_C1))[tid] = make_float4(0.f, 0.f, 0.f, 0.f);
}

// Stage 1: C1[b][he][c] += sum_{l in K-slice} q[b][l][he] * basF[l][c]
// grid (ks=32, rt=4, b=4); 128x128 tile, K-slice of 128 per block, chunks of 64.
__global__ __launch_bounds__(256, 2) void k_dft(const float* __restrict__ q,
                                                float* __restrict__ ws) {
    __shared__ float As[64][128];
    __shared__ float Bs[64][128];
    const float* basF = ws + OFF_BASF;
    float* C1 = ws + OFF_C1;
    const int b = blockIdx.z, rt = blockIdx.y, ks = blockIdx.x;
    const int he0 = rt * 128;
    const int t = threadIdx.x, tx = t & 15, ty = t >> 4;
    float acc[8][8] = {};

    const int kbeg = ks * 128;
    for (int k0 = kbeg; k0 < kbeg + 128; k0 += 64) {
#pragma unroll
        for (int it = 0; it < 8; ++it) {
            int idx = t + it * 256;           // 0..2047
            int kk = idx >> 5;                // 64 rows, 32 float4/row
            int c4 = (idx & 31) << 2;
            *(float4*)(&As[kk][c4]) =
                *(const float4*)(q + ((size_t)(b * Lsz + k0 + kk) * HEsz + he0 + c4));
            *(float4*)(&Bs[kk][c4]) =
                *(const float4*)(basF + (size_t)(k0 + kk) * CCsz + c4);
        }
        __syncthreads();
#pragma unroll 4
        for (int kk = 0; kk < 64; ++kk) {
            float a[8], bb[8];
            *(float4*)(a)     = *(float4*)(&As[kk][ty * 8]);
            *(float4*)(a + 4) = *(float4*)(&As[kk][ty * 8 + 4]);
            *(float4*)(bb)     = *(float4*)(&Bs[kk][tx * 8]);
            *(float4*)(bb + 4) = *(float4*)(&Bs[kk][tx * 8 + 4]);
#pragma unroll
            for (int i = 0; i < 8; ++i)
#pragma unroll
                for (int j = 0; j < 8; ++j)
                    acc[i][j] = fmaf(a[i], bb[j], acc[i][j]);
        }
        __syncthreads();
    }
#pragma unroll
    for (int i = 0; i < 8; ++i)
#pragma unroll
        for (int j = 0; j < 8; ++j)
            atomicAdd(&C1[(size_t)b * HEsz * CCsz + (size_t)(he0 + ty * 8 + i) * CCsz + tx * 8 + j],
                      acc[i][j]);
}

// Stage 2: head mixing + irfft scaling.
// res[b,o,e,m] = sum_i X[b,i,e,m] * (wr + i wi)[i,o,e,m]
// Cf[row][2m] = wm*Re(res), Cf[row][2m+1] = -wm*Im(res), wm = (m==0?1:2)/L
__global__ __launch_bounds__(256) void k_mix(const float* __restrict__ wr_,
                                             const float* __restrict__ wi_,
                                             float* __restrict__ ws) {
    int tid = blockIdx.x * 256 + threadIdx.x;   // 131072
    int m = tid & 63, e = (tid >> 6) & 63, o = (tid >> 12) & 7, b = tid >> 15;
    const float* C1 = ws + OFF_C1;
    float* Cf = ws + OFF_CF;
    float ar = 0.f, ai = 0.f;
#pragma unroll
    for (int i = 0; i < 8; ++i) {
        float xr = C1[((size_t)b * HEsz + i * 64 + e) * CCsz + 2 * m];
        float xi = C1[((size_t)b * HEsz + i * 64 + e) * CCsz + 2 * m + 1];
        float wr = wr_[(((size_t)(i * 8 + o) * 64 + e) * 64) + m];
        float wi = wi_[(((size_t)(i * 8 + o) * 64 + e) * 64) + m];
        ar += xr * wr - xi * wi;
        ai += xr * wi + xi * wr;
    }
    float wm = (m == 0) ? (1.0f / (float)Lsz) : (2.0f / (float)Lsz);
    int row = b * 512 + o * 64 + e;
    Cf[(size_t)row * CCsz + 2 * m] = wm * ar;
    Cf[(size_t)row * CCsz + 2 * m + 1] = -wm * ai;
}

// Stage 3: out[row][l] = sum_{k=0}^{127} Cf[row][k] * basI[k][l]
// grid (lt=32, rt=16); 128x128 tile, full K=128 in two 64-chunks.
// As is transposed during staging with XOR-column swizzle (s = ((k>>2)&3)*8)
// to keep staging writes at 4-way conflict and compute reads conflict-free.
__global__ __launch_bounds__(256, 2) void k_idft(const float* __restrict__ ws,
                                                 float* __restrict__ out) {
    __shared__ float As[64][128];
    __shared__ float Bs[64][128];
    const float* basI = ws + OFF_BASI;
    const float* Cf = ws + OFF_CF;
    const int l0 = blockIdx.x * 128, row0 = blockIdx.y * 128;
    const int t = threadIdx.x, tx = t & 15, ty = t >> 4;
    float acc[8][8] = {};

    for (int k0 = 0; k0 < 128; k0 += 64) {
#pragma unroll
        for (int it = 0; it < 8; ++it) {
            int idx = t + it * 256;           // 0..2047
            // A: 128 rows x 64 k, transpose into As[k][row^swz]
            int r = idx >> 4;
            int k4 = (idx & 15) << 2;
            float4 v = *(const float4*)(Cf + (size_t)(row0 + r) * CCsz + k0 + k4);
            int s = ((k4 >> 2) & 3) << 3;     // same for k4..k4+3
            As[k4 + 0][r ^ s] = v.x;
            As[k4 + 1][r ^ s] = v.y;
            As[k4 + 2][r ^ s] = v.z;
            As[k4 + 3][r ^ s] = v.w;
            // B: 64 k x 128 l, direct copy
            int kk = idx >> 5;
            int c4 = (idx & 31) << 2;
            *(float4*)(&Bs[kk][c4]) =
                *(const float4*)(basI + (size_t)(k0 + kk) * Lsz + l0 + c4);
        }
        __syncthreads();
#pragma unroll 4
        for (int kk = 0; kk < 64; ++kk) {
            float a[8], bb[8];
            int s = ((kk >> 2) & 3) << 3;
            int ca = (ty * 8) ^ s;
            *(float4*)(a)     = *(float4*)(&As[kk][ca]);
            *(float4*)(a + 4) = *(float4*)(&As[kk][ca + 4]);
            *(float4*)(bb)     = *(float4*)(&Bs[kk][tx * 8]);
            *(float4*)(bb + 4) = *(float4*)(&Bs[kk][tx * 8 + 4]);
#pragma unroll
            for (int i = 0; i < 8; ++i)
#pragma unroll
                for (int j = 0; j < 8; ++j)
                    acc[i][j] = fmaf(a[i], bb[j], acc[i][j]);
        }
        __syncthreads();
    }
#pragma unroll
    for (int i = 0; i < 8; ++i) {
        int row = row0 + ty * 8 + i;
        float4 o1 = make_float4(acc[i][0], acc[i][1], acc[i][2], acc[i][3]);
        float4 o2 = make_float4(acc[i][4], acc[i][5], acc[i][6], acc[i][7]);
        *(float4*)(out + (size_t)row * Lsz + l0 + tx * 8)     = o1;
        *(float4*)(out + (size_t)row * Lsz + l0 + tx * 8 + 4) = o2;
    }
}

extern "C" void kernel_launch(void* const* d_in, const int* in_sizes, int n_in,
                              void* d_out, int out_size, void* d_ws, size_t ws_size,
                              hipStream_t stream) {
    const float* q      = (const float*)d_in[0];
    // d_in[1] = k, d_in[2] = v: unused by the reference
    const float* w_real = (const float*)d_in[3];
    const float* w_imag = (const float*)d_in[4];
    // d_in[5] = index (arange(64), static), d_in[6] = mask (unused)
    float* out = (float*)d_out;
    float* ws  = (float*)d_ws;   // needs 6 MiB

    k_tableF<<<2048, 256, 0, stream>>>(ws);
    k_tableI<<<2048, 256, 0, stream>>>(ws);
    k_zero  <<<256,  256, 0, stream>>>(ws);
    k_dft   <<<dim3(32, 4, 4), 256, 0, stream>>>(q, ws);
    k_mix   <<<512,  256, 0, stream>>>(w_real, w_imag, ws);
    k_idft  <<<dim3(32, 16), 256, 0, stream>>>(ws, out);
}

// Round 2
// 201.153 us; speedup vs baseline: 1.9650x; 1.9650x over previous
//
#include <hip/hip_runtime.h>
#include <math.h>

// Problem constants (B,L,H,E,M) = (4,4096,8,64,64)
#define Bsz 4
#define Lsz 4096
#define Hsz 8
#define Esz 64
#define Msz 64
#define HEsz 512     // H*E
#define CCsz 128     // 2*M interleaved (re,im)
#define ROWS 2048    // B*H*E

// workspace layout in floats
#define OFF_BASF 0                         // [L][CC]   forward basis (524288)
#define OFF_BASI (Lsz*CCsz)                // [CC][L]   inverse basis (524288)
#define OFF_C1   (2*Lsz*CCsz)             // [B][HE][CC] reduced DFT output (262144)
#define OFF_CF   (OFF_C1 + Bsz*HEsz*CCsz) // [ROWS][CC] mixed+scaled coeffs (262144)
#define OFF_C1P  (OFF_CF + ROWS*CCsz)     // [split][B][HE][CC] partials (split*262144)
#define C1SZ     (Bsz*HEsz*CCsz)          // 262144 floats = 1 MiB

static __device__ __forceinline__ float2 twiddle(int m, int l) {
    // exact mod since L = 4096: angle = 2*pi*((m*l) mod L)/L
    int r = (m * l) & (Lsz - 1);
    float ang = (float)r * (6.283185307179586f / (float)Lsz);
    float s, c;
    __sincosf(ang, &s, &c);
    return make_float2(c, s);
}

// forward basis: basF[l*128 + 2m] = cos, basF[l*128 + 2m+1] = -sin  (rfft: e^{-i t})
__global__ __launch_bounds__(256) void k_tableF(float* __restrict__ ws) {
    int tid = blockIdx.x * 256 + threadIdx.x;   // 524288
    int l = tid >> 7, c = tid & 127;
    int m = c >> 1;
    float2 cs = twiddle(m, l);
    ws[OFF_BASF + tid] = (c & 1) ? -cs.y : cs.x;
}

// inverse basis: basI[(2m)*4096 + l] = cos, basI[(2m+1)*4096 + l] = sin
__global__ __launch_bounds__(256) void k_tableI(float* __restrict__ ws) {
    int tid = blockIdx.x * 256 + threadIdx.x;   // 524288
    int k = tid >> 12, l = tid & 4095;
    int m = k >> 1;
    float2 cs = twiddle(m, l);
    ws[OFF_BASI + tid] = (k & 1) ? cs.y : cs.x;
}

// Stage 1: C1P[ks][b][he][c] = sum_{l in K-slice ks} q[b][l][he] * basF[l][c]
// grid (split, 4, 4); 128x128 output tile per block, plain stores (no atomics).
__global__ __launch_bounds__(256, 2) void k_dft(const float* __restrict__ q,
                                                float* __restrict__ ws,
                                                int c1pOff, int KS) {
    __shared__ float As[64][128];
    __shared__ float Bs[64][128];
    const float* basF = ws + OFF_BASF;
    const int b = blockIdx.z, rt = blockIdx.y, ks = blockIdx.x;
    float* C1P = ws + c1pOff + (size_t)ks * C1SZ;
    const int he0 = rt * 128;
    const int t = threadIdx.x, tx = t & 15, ty = t >> 4;
    float acc[8][8] = {};

    const int kbeg = ks * KS;
    for (int k0 = kbeg; k0 < kbeg + KS; k0 += 64) {
#pragma unroll
        for (int it = 0; it < 8; ++it) {
            int idx = t + it * 256;           // 0..2047
            int kk = idx >> 5;                // 64 rows, 32 float4/row
            int c4 = (idx & 31) << 2;
            *(float4*)(&As[kk][c4]) =
                *(const float4*)(q + ((size_t)(b * Lsz + k0 + kk) * HEsz + he0 + c4));
            *(float4*)(&Bs[kk][c4]) =
                *(const float4*)(basF + (size_t)(k0 + kk) * CCsz + c4);
        }
        __syncthreads();
#pragma unroll 4
        for (int kk = 0; kk < 64; ++kk) {
            float a[8], bb[8];
            *(float4*)(a)     = *(float4*)(&As[kk][ty * 8]);
            *(float4*)(a + 4) = *(float4*)(&As[kk][ty * 8 + 4]);
            *(float4*)(bb)     = *(float4*)(&Bs[kk][tx * 8]);
            *(float4*)(bb + 4) = *(float4*)(&Bs[kk][tx * 8 + 4]);
#pragma unroll
            for (int i = 0; i < 8; ++i)
#pragma unroll
                for (int j = 0; j < 8; ++j)
                    acc[i][j] = fmaf(a[i], bb[j], acc[i][j]);
        }
        __syncthreads();
    }
#pragma unroll
    for (int i = 0; i < 8; ++i) {
        float* dst = C1P + ((size_t)b * HEsz + he0 + ty * 8 + i) * CCsz + tx * 8;
        *(float4*)(dst)     = make_float4(acc[i][0], acc[i][1], acc[i][2], acc[i][3]);
        *(float4*)(dst + 4) = make_float4(acc[i][4], acc[i][5], acc[i][6], acc[i][7]);
    }
}

// Reduce split-K partials: C1[idx] = sum_s C1P[s][idx]  (float4 per thread)
__global__ __launch_bounds__(256) void k_reduce(float* __restrict__ ws,
                                                int c1pOff, int split) {
    int tid = blockIdx.x * 256 + threadIdx.x;   // 65536
    const float4* src = (const float4*)(ws + c1pOff);
    float4 s = src[tid];
    for (int p = 1; p < split; ++p) {
        float4 v = src[(size_t)p * (C1SZ / 4) + tid];
        s.x += v.x; s.y += v.y; s.z += v.z; s.w += v.w;
    }
    ((float4*)(ws + OFF_C1))[tid] = s;
}

// Stage 2: head mixing + irfft scaling.
// res[b,o,e,m] = sum_i X[b,i,e,m] * (wr + i wi)[i,o,e,m]
// Cf[row][2m] = wm*Re(res), Cf[row][2m+1] = -wm*Im(res), wm = (m==0?1:2)/L
__global__ __launch_bounds__(256) void k_mix(const float* __restrict__ wr_,
                                             const float* __restrict__ wi_,
                                             float* __restrict__ ws) {
    int tid = blockIdx.x * 256 + threadIdx.x;   // 131072
    int m = tid & 63, e = (tid >> 6) & 63, o = (tid >> 12) & 7, b = tid >> 15;
    const float* C1 = ws + OFF_C1;
    float* Cf = ws + OFF_CF;
    float ar = 0.f, ai = 0.f;
#pragma unroll
    for (int i = 0; i < 8; ++i) {
        float xr = C1[((size_t)b * HEsz + i * 64 + e) * CCsz + 2 * m];
        float xi = C1[((size_t)b * HEsz + i * 64 + e) * CCsz + 2 * m + 1];
        float wr = wr_[(((size_t)(i * 8 + o) * 64 + e) * 64) + m];
        float wi = wi_[(((size_t)(i * 8 + o) * 64 + e) * 64) + m];
        ar += xr * wr - xi * wi;
        ai += xr * wi + xi * wr;
    }
    float wm = (m == 0) ? (1.0f / (float)Lsz) : (2.0f / (float)Lsz);
    int row = b * 512 + o * 64 + e;
    Cf[(size_t)row * CCsz + 2 * m] = wm * ar;
    Cf[(size_t)row * CCsz + 2 * m + 1] = -wm * ai;
}

// Stage 3: out[row][l] = sum_{k=0}^{127} Cf[row][k] * basI[k][l]
// grid (lt=32, rt=16); 128x128 tile, full K=128 in two 64-chunks.
// As transposed during staging with XOR-column swizzle to stay conflict-light.
__global__ __launch_bounds__(256, 2) void k_idft(const float* __restrict__ ws,
                                                 float* __restrict__ out) {
    __shared__ float As[64][128];
    __shared__ float Bs[64][128];
    const float* basI = ws + OFF_BASI;
    const float* Cf = ws + OFF_CF;
    const int l0 = blockIdx.x * 128, row0 = blockIdx.y * 128;
    const int t = threadIdx.x, tx = t & 15, ty = t >> 4;
    float acc[8][8] = {};

    for (int k0 = 0; k0 < 128; k0 += 64) {
#pragma unroll
        for (int it = 0; it < 8; ++it) {
            int idx = t + it * 256;           // 0..2047
            // A: 128 rows x 64 k, transpose into As[k][row^swz]
            int r = idx >> 4;
            int k4 = (idx & 15) << 2;
            float4 v = *(const float4*)(Cf + (size_t)(row0 + r) * CCsz + k0 + k4);
            int s = ((k4 >> 2) & 3) << 3;     // same for k4..k4+3
            As[k4 + 0][r ^ s] = v.x;
            As[k4 + 1][r ^ s] = v.y;
            As[k4 + 2][r ^ s] = v.z;
            As[k4 + 3][r ^ s] = v.w;
            // B: 64 k x 128 l, direct copy
            int kk = idx >> 5;
            int c4 = (idx & 31) << 2;
            *(float4*)(&Bs[kk][c4]) =
                *(const float4*)(basI + (size_t)(k0 + kk) * Lsz + l0 + c4);
        }
        __syncthreads();
#pragma unroll 4
        for (int kk = 0; kk < 64; ++kk) {
            float a[8], bb[8];
            int s = ((kk >> 2) & 3) << 3;
            int ca = (ty * 8) ^ s;
            *(float4*)(a)     = *(float4*)(&As[kk][ca]);
            *(float4*)(a + 4) = *(float4*)(&As[kk][ca + 4]);
            *(float4*)(bb)     = *(float4*)(&Bs[kk][tx * 8]);
            *(float4*)(bb + 4) = *(float4*)(&Bs[kk][tx * 8 + 4]);
#pragma unroll
            for (int i = 0; i < 8; ++i)
#pragma unroll
                for (int j = 0; j < 8; ++j)
                    acc[i][j] = fmaf(a[i], bb[j], acc[i][j]);
        }
        __syncthreads();
    }
#pragma unroll
    for (int i = 0; i < 8; ++i) {
        int row = row0 + ty * 8 + i;
        float4 o1 = make_float4(acc[i][0], acc[i][1], acc[i][2], acc[i][3]);
        float4 o2 = make_float4(acc[i][4], acc[i][5], acc[i][6], acc[i][7]);
        *(float4*)(out + (size_t)row * Lsz + l0 + tx * 8)     = o1;
        *(float4*)(out + (size_t)row * Lsz + l0 + tx * 8 + 4) = o2;
    }
}

extern "C" void kernel_launch(void* const* d_in, const int* in_sizes, int n_in,
                              void* d_out, int out_size, void* d_ws, size_t ws_size,
                              hipStream_t stream) {
    const float* q      = (const float*)d_in[0];
    // d_in[1] = k, d_in[2] = v: unused by the reference
    const float* w_real = (const float*)d_in[3];
    const float* w_imag = (const float*)d_in[4];
    // d_in[5] = index (arange(64), static), d_in[6] = mask (unused)
    float* out = (float*)d_out;
    float* ws  = (float*)d_ws;

    // pick split-K so the partial buffer fits in ws (split=1 -> 6 MiB, always
    // the round-1 footprint; split=32 -> ~38.5 MiB)
    int split = 32;
    while (split > 1 &&
           (size_t)(OFF_C1P + (size_t)split * C1SZ) * sizeof(float) > ws_size)
        split >>= 1;
    // split==1: write partials directly into C1, skip the reduce
    int c1pOff = (split == 1) ? OFF_C1 : OFF_C1P;
    int KS = Lsz / split;

    k_tableF<<<2048, 256, 0, stream>>>(ws);
    k_tableI<<<2048, 256, 0, stream>>>(ws);
    k_dft   <<<dim3(split, 4, 4), 256, 0, stream>>>(q, ws, c1pOff, KS);
    if (split > 1)
        k_reduce<<<256, 256, 0, stream>>>(ws, c1pOff, split);
    k_mix   <<<512,  256, 0, stream>>>(w_real, w_imag, ws);
    k_idft  <<<dim3(32, 16), 256, 0, stream>>>(ws, out);
}

// Round 3
// 146.807 us; speedup vs baseline: 2.6924x; 1.3702x over previous
//
#include <hip/hip_runtime.h>

// Problem constants (B,L,H,E,M) = (4,4096,8,64,64)
#define Bsz 4
#define Lsz 4096
#define HEsz 512      // H*E rows per batch
#define SPLIT 16      // split-K for the forward DFT

typedef __attribute__((ext_vector_type(8))) short short8;
typedef __attribute__((ext_vector_type(4))) float f32x4;

// workspace byte offsets (total 19 MiB; round-2 confirmed ws >= 38.5 MiB)
#define OFF_BASFT 0u                 // ushort[128][4096]  forward basis, c-major l-contig
#define OFF_BASIT (1u<<20)           // ushort[4096][128]  inverse basis, l-major k-contig (wm folded)
#define OFF_CF    (2u<<20)           // ushort[2048][128]  mixed coeffs bf16
#define OFF_C1P   (3u<<20)           // float[SPLIT][4][512][128] split-K partials

static __device__ __forceinline__ unsigned short f2bf(float f) {
    union { float f; unsigned u; } v; v.f = f;
    unsigned u = v.u;
    return (unsigned short)((u + 0x7fffu + ((u >> 16) & 1u)) >> 16);   // RNE
}
static __device__ __forceinline__ unsigned pk2(float a, float b) {
    return (unsigned)f2bf(a) | ((unsigned)f2bf(b) << 16);
}
static __device__ __forceinline__ void sc(int m, int l, float* s, float* c) {
    int r = (m * l) & (Lsz - 1);                       // exact mod, L = 4096
    float ang = (float)r * (6.283185307179586f / (float)Lsz);
    __sincosf(ang, s, c);
}

// ---- table generation: both bf16 transposed bases in one kernel (512 blocks) ----
__global__ __launch_bounds__(256) void k_tables(unsigned short* __restrict__ basFT,
                                                unsigned short* __restrict__ basIT) {
    int bid = blockIdx.x, t = threadIdx.x;
    if (bid < 256) {
        // basFT[c][l]: c=2m -> cos, c=2m+1 -> -sin   (rfft: e^{-i theta})
        int tid = bid * 256 + t;                 // 65536
        int c = tid >> 9, lg = tid & 511;        // 8 l's per thread
        int m = c >> 1, im = c & 1;
        float v[8];
#pragma unroll
        for (int j = 0; j < 8; ++j) {
            float s, co; sc(m, lg * 8 + j, &s, &co);
            v[j] = im ? -s : co;
        }
        uint4 o = make_uint4(pk2(v[0], v[1]), pk2(v[2], v[3]), pk2(v[4], v[5]), pk2(v[6], v[7]));
        *(uint4*)(basFT + (size_t)c * Lsz + lg * 8) = o;
    } else {
        // basIT[l][2m] = wm*cos, [2m+1] = wm*sin ; wm = (m==0?1:2)/L
        int tid = (bid - 256) * 256 + t;         // 65536
        int l = tid >> 4, mg = tid & 15;         // 4 m's (8 k) per thread
        unsigned w[4];
#pragma unroll
        for (int jm = 0; jm < 4; ++jm) {
            int m = mg * 4 + jm;
            float s, co; sc(m, l, &s, &co);
            float wm = (m == 0) ? (1.0f / Lsz) : (2.0f / Lsz);
            w[jm] = pk2(wm * co, wm * s);
        }
        *(uint4*)(basIT + (size_t)l * 128 + mg * 8) = make_uint4(w[0], w[1], w[2], w[3]);
    }
}

// ---- Stage 1: forward truncated DFT, bf16 MFMA, split-K fp32 partials ----
// C1P[ks][b][he][c] = sum_{l in slice} q[b][l][he] * basFT[c][l]
// grid (SPLIT, 8 he-tiles, 4 b) = 512 blocks; tile 64he x 128c, K-slice 256.
__global__ __launch_bounds__(256, 2) void k_dft(const float* __restrict__ q,
                                                const unsigned short* __restrict__ basFT,
                                                float* __restrict__ C1P) {
    __shared__ unsigned short As[64 * 64];    // [he][l], XOR-swizzled 8-blocks, 8 KB
    __shared__ unsigned short Bs[128 * 64];   // [c][l],  XOR-swizzled 8-blocks, 16 KB
    const int ks = blockIdx.x, ht = blockIdx.y, b = blockIdx.z;
    const int he0 = ht * 64;
    const int t = threadIdx.x, lane = t & 63, w = t >> 6;
    const int wm = w & 1, wn = w >> 1;        // wave tile: 32he x 64c
    const int quad = lane >> 4, lid = lane & 15;
    f32x4 acc[2][4] = {};

    const int kbeg = ks * (Lsz / SPLIT);
    for (int ch = 0; ch < 4; ++ch) {
        const int l0 = kbeg + ch * 64;
        // A: transpose-convert q. wave w covers l = w*16..w*16+15, lane = he.
        {
            const float* qp = q + ((size_t)(b * Lsz + l0 + w * 16) * HEsz + he0 + lane);
            float f[16];
#pragma unroll
            for (int j = 0; j < 16; ++j) f[j] = qp[(size_t)j * HEsz];
            uint4 p0 = make_uint4(pk2(f[0], f[1]), pk2(f[2], f[3]), pk2(f[4], f[5]), pk2(f[6], f[7]));
            uint4 p1 = make_uint4(pk2(f[8], f[9]), pk2(f[10], f[11]), pk2(f[12], f[13]), pk2(f[14], f[15]));
            int row = lane;
            int cb0 = (w * 2) ^ (row & 7), cb1 = (w * 2 + 1) ^ (row & 7);
            *(uint4*)(As + row * 64 + cb0 * 8) = p0;
            *(uint4*)(As + row * 64 + cb1 * 8) = p1;
        }
        // B: copy basFT tile (already bf16, l-contig)
#pragma unroll
        for (int it = 0; it < 4; ++it) {
            int slot = t + it * 256;              // 1024: c = slot>>3, cb = slot&7
            int c = slot >> 3, cb = slot & 7;
            uint4 v = *(const uint4*)(basFT + (size_t)c * Lsz + l0 + cb * 8);
            *(uint4*)(Bs + c * 64 + ((cb ^ (c & 7)) * 8)) = v;
        }
        __syncthreads();
#pragma unroll
        for (int kst = 0; kst < 2; ++kst) {
            short8 af[2], bfr[4];
#pragma unroll
            for (int mt = 0; mt < 2; ++mt) {
                int m = wm * 32 + mt * 16 + lid;
                int cb = (kst * 4 + quad) ^ (m & 7);
                af[mt] = *(short8*)(As + m * 64 + cb * 8);
            }
#pragma unroll
            for (int nt = 0; nt < 4; ++nt) {
                int n = wn * 64 + nt * 16 + lid;
                int cb = (kst * 4 + quad) ^ (n & 7);
                bfr[nt] = *(short8*)(Bs + n * 64 + cb * 8);
            }
#pragma unroll
            for (int mt = 0; mt < 2; ++mt)
#pragma unroll
                for (int nt = 0; nt < 4; ++nt)
                    acc[mt][nt] = __builtin_amdgcn_mfma_f32_16x16x32_bf16(af[mt], bfr[nt], acc[mt][nt], 0, 0, 0);
        }
        __syncthreads();
    }
    // epilogue: C/D layout col=lane&15, row=quad*4+reg
    float* dst = C1P + (((size_t)ks * Bsz + b) * HEsz + he0) * 128;
#pragma unroll
    for (int mt = 0; mt < 2; ++mt)
#pragma unroll
        for (int nt = 0; nt < 4; ++nt)
#pragma unroll
            for (int r = 0; r < 4; ++r)
                dst[(size_t)(wm * 32 + mt * 16 + quad * 4 + r) * 128 + wn * 64 + nt * 16 + lid] =
                    acc[mt][nt][r];
}

// ---- Stage 2: fused split-K reduce + head mixing, bf16 Cf output ----
// grid (4b * 64e) = 256 blocks. Block reduces X[i=8][c=128] over SPLIT partials,
// then res[o,m] = sum_i X[i,m] * w[i,o,e,m]; Cf = (Re, -Im) bf16 (wm folded in basIT).
__global__ __launch_bounds__(256) void k_mixreduce(const float* __restrict__ C1P,
                                                   const float* __restrict__ wr,
                                                   const float* __restrict__ wi,
                                                   unsigned short* __restrict__ Cf) {
    __shared__ float X[8][128];
    const int e = blockIdx.x & 63, b = blockIdx.x >> 6;
    const int t = threadIdx.x;
    const int i = t >> 5, c4 = t & 31;
    const float4* base = (const float4*)(C1P + (((size_t)b * HEsz + i * 64 + e) * 128)) + c4;
    float4 s = make_float4(0.f, 0.f, 0.f, 0.f);
    for (int sp = 0; sp < SPLIT; ++sp) {
        float4 v = base[(size_t)sp * (Bsz * HEsz * 128 / 4)];
        s.x += v.x; s.y += v.y; s.z += v.z; s.w += v.w;
    }
    *(float4*)&X[i][c4 * 4] = s;
    __syncthreads();
#pragma unroll
    for (int it = 0; it < 2; ++it) {
        int item = t + it * 256;                 // 512: o = item>>6, m = item&63
        int o = item >> 6, m = item & 63;
        float ar = 0.f, ai = 0.f;
#pragma unroll
        for (int i2 = 0; i2 < 8; ++i2) {
            float xr = X[i2][2 * m], xi = X[i2][2 * m + 1];
            size_t wo = ((size_t)(i2 * 8 + o) * 64 + e) * 64 + m;
            float wrv = wr[wo], wiv = wi[wo];
            ar += xr * wrv - xi * wiv;
            ai += xr * wiv + xi * wrv;
        }
        int row = b * HEsz + o * 64 + e;
        *(unsigned*)(Cf + (size_t)row * 128 + 2 * m) = pk2(ar, -ai);
    }
}

// ---- Stage 3: truncated irfft, bf16 MFMA ----
// out[row][l] = sum_k Cf[row][k] * basIT_T[k][l]; grid (32 lt, 16 rt), tile 128x128, K=128.
__global__ __launch_bounds__(256, 2) void k_idft(const unsigned short* __restrict__ Cf,
                                                 const unsigned short* __restrict__ basIT,
                                                 float* __restrict__ out) {
    __shared__ unsigned short As[128 * 128];  // [row][k] swz16, 32 KB
    __shared__ unsigned short Bs[128 * 128];  // [l][k]  swz16, 32 KB
    const int l0 = blockIdx.x * 128, row0 = blockIdx.y * 128;
    const int t = threadIdx.x, lane = t & 63, w = t >> 6;
    const int wm = w & 1, wn = w >> 1;        // wave tile 64 x 64
    const int quad = lane >> 4, lid = lane & 15;
#pragma unroll
    for (int it = 0; it < 8; ++it) {
        int slot = t + it * 256;              // 2048: r = slot>>4, cb = slot&15
        int r = slot >> 4, cb = slot & 15;
        uint4 a = *(const uint4*)(Cf + (size_t)(row0 + r) * 128 + cb * 8);
        *(uint4*)(As + r * 128 + ((cb ^ (r & 15)) * 8)) = a;
        uint4 bv = *(const uint4*)(basIT + (size_t)(l0 + r) * 128 + cb * 8);
        *(uint4*)(Bs + r * 128 + ((cb ^ (r & 15)) * 8)) = bv;
    }
    __syncthreads();
    f32x4 acc[4][4] = {};
#pragma unroll
    for (int kst = 0; kst < 4; ++kst) {
        short8 af[4], bfr[4];
#pragma unroll
        for (int mt = 0; mt < 4; ++mt) {
            int m = wm * 64 + mt * 16 + lid;
            int cb = (kst * 4 + quad) ^ (m & 15);
            af[mt] = *(short8*)(As + m * 128 + cb * 8);
        }
#pragma unroll
        for (int nt = 0; nt < 4; ++nt) {
            int n = wn * 64 + nt * 16 + lid;
            int cb = (kst * 4 + quad) ^ (n & 15);
            bfr[nt] = *(short8*)(Bs + n * 128 + cb * 8);
        }
#pragma unroll
        for (int mt = 0; mt < 4; ++mt)
#pragma unroll
            for (int nt = 0; nt < 4; ++nt)
                acc[mt][nt] = __builtin_amdgcn_mfma_f32_16x16x32_bf16(af[mt], bfr[nt], acc[mt][nt], 0, 0, 0);
    }
    __syncthreads();
    // transpose through LDS (reuse As/Bs as float[128][128]) for float4 stores
    float* outb = (float*)As;
#pragma unroll
    for (int mt = 0; mt < 4; ++mt)
#pragma unroll
        for (int nt = 0; nt < 4; ++nt)
#pragma unroll
            for (int r = 0; r < 4; ++r)
                outb[(size_t)(wm * 64 + mt * 16 + quad * 4 + r) * 128 + wn * 64 + nt * 16 + lid] =
                    acc[mt][nt][r];
    __syncthreads();
#pragma unroll
    for (int it = 0; it < 16; ++it) {
        int slot = t + it * 256;              // 4096 float4: r = slot>>5, c4 = slot&31
        int r = slot >> 5, c4 = slot & 31;
        float4 v = *(float4*)(outb + (size_t)r * 128 + c4 * 4);
        *(float4*)(out + (size_t)(row0 + r) * Lsz + l0 + c4 * 4) = v;
    }
}

extern "C" void kernel_launch(void* const* d_in, const int* in_sizes, int n_in,
                              void* d_out, int out_size, void* d_ws, size_t ws_size,
                              hipStream_t stream) {
    const float* q      = (const float*)d_in[0];
    const float* w_real = (const float*)d_in[3];
    const float* w_imag = (const float*)d_in[4];
    float* out = (float*)d_out;
    char* ws = (char*)d_ws;                 // needs 19 MiB (have ~38.5+)

    unsigned short* basFT = (unsigned short*)(ws + OFF_BASFT);
    unsigned short* basIT = (unsigned short*)(ws + OFF_BASIT);
    unsigned short* Cf    = (unsigned short*)(ws + OFF_CF);
    float*          C1P   = (float*)(ws + OFF_C1P);

    k_tables   <<<512, 256, 0, stream>>>(basFT, basIT);
    k_dft      <<<dim3(SPLIT, 8, 4), 256, 0, stream>>>(q, basFT, C1P);
    k_mixreduce<<<256, 256, 0, stream>>>(C1P, w_real, w_imag, Cf);
    k_idft     <<<dim3(32, 16), 256, 0, stream>>>(Cf, basIT, out);
}

// Round 4
// 145.069 us; speedup vs baseline: 2.7246x; 1.0120x over previous
//
#include <hip/hip_runtime.h>

// Problem constants (B,L,H,E,M) = (4,4096,8,64,64)
#define Bsz 4
#define Lsz 4096
#define HEsz 512      // H*E rows per batch
#define SPLIT 16      // split-K for the forward DFT

typedef __attribute__((ext_vector_type(8))) short short8;
typedef __attribute__((ext_vector_type(4))) float f32x4;

// workspace byte offsets (total ~9 MiB; ws is 256 MiB)
#define OFF_CF  0u        // ushort[2048][128] mixed coeffs bf16 (512 KB)
#define OFF_C1P (1u<<20)  // ushort[SPLIT][4][512][128] split-K partials bf16 (8 MB)

static __device__ __forceinline__ unsigned short f2bf(float f) {
    union { float f; unsigned u; } v; v.f = f;
    unsigned u = v.u;
    return (unsigned short)((u + 0x7fffu + ((u >> 16) & 1u)) >> 16);   // RNE
}
static __device__ __forceinline__ unsigned pk2(float a, float b) {
    return (unsigned)f2bf(a) | ((unsigned)f2bf(b) << 16);
}
static __device__ __forceinline__ float bf2f(unsigned short u) {
    union { unsigned u; float f; } v; v.u = ((unsigned)u) << 16;
    return v.f;
}
static __device__ __forceinline__ void sc(int m, int l, float* s, float* c) {
    int r = (m * l) & (Lsz - 1);                       // exact mod, L = 4096
    float ang = (float)r * (6.283185307179586f / (float)Lsz);
    __sincosf(ang, s, c);
}

// ---- Stage 1: forward truncated DFT, bf16 MFMA, split-K bf16 partials ----
// C1P[ks][b][he][c] = sum_{l in slice} q[b][l][he] * basF[c][l]
// basF generated in-kernel: c=2m -> cos(2pi m l/L), c=2m+1 -> -sin (rfft e^{-i t})
// grid (SPLIT, 8 he-tiles, 4 b) = 512 blocks; tile 64he x 128c, K-slice 256.
__global__ __launch_bounds__(256, 2) void k_dft(const float* __restrict__ q,
                                                unsigned short* __restrict__ C1P) {
    __shared__ unsigned short As[64 * 64];    // [he][l], XOR-swizzled 8-blocks, 8 KB
    __shared__ unsigned short Bs[128 * 64];   // [c][l],  XOR-swizzled 8-blocks, 16 KB
    const int ks = blockIdx.x, ht = blockIdx.y, b = blockIdx.z;
    const int he0 = ht * 64;
    const int t = threadIdx.x, lane = t & 63, w = t >> 6;
    const int wtm = w & 1, wtn = w >> 1;      // wave tile: 32he x 64c
    const int quad = lane >> 4, lid = lane & 15;
    f32x4 acc[2][4] = {};

    const int kbeg = ks * (Lsz / SPLIT);
    for (int ch = 0; ch < 4; ++ch) {
        const int l0 = kbeg + ch * 64;
        // A: transpose-convert q. wave w covers l = w*16..w*16+15, lane = he.
        {
            const float* qp = q + ((size_t)(b * Lsz + l0 + w * 16) * HEsz + he0 + lane);
            float f[16];
#pragma unroll
            for (int j = 0; j < 16; ++j) f[j] = qp[(size_t)j * HEsz];
            uint4 p0 = make_uint4(pk2(f[0], f[1]), pk2(f[2], f[3]), pk2(f[4], f[5]), pk2(f[6], f[7]));
            uint4 p1 = make_uint4(pk2(f[8], f[9]), pk2(f[10], f[11]), pk2(f[12], f[13]), pk2(f[14], f[15]));
            int row = lane;
            int cb0 = (w * 2) ^ (row & 7), cb1 = (w * 2 + 1) ^ (row & 7);
            *(uint4*)(As + row * 64 + cb0 * 8) = p0;
            *(uint4*)(As + row * 64 + cb1 * 8) = p1;
        }
        // B: generate basF tile in-register. thread -> m = t&63, 16 l's.
        {
            int m = t & 63, lg = t >> 6;      // lg in [0,4): l-sub = lg*16..+16
            int c0 = 2 * m, c1 = 2 * m + 1;
#pragma unroll
            for (int h = 0; h < 2; ++h) {     // two 8-l halves
                float sv[8], cv[8];
#pragma unroll
                for (int j = 0; j < 8; ++j)
                    sc(m, l0 + lg * 16 + h * 8 + j, &sv[j], &cv[j]);
                uint4 pc = make_uint4(pk2(cv[0], cv[1]), pk2(cv[2], cv[3]),
                                      pk2(cv[4], cv[5]), pk2(cv[6], cv[7]));
                uint4 ps = make_uint4(pk2(-sv[0], -sv[1]), pk2(-sv[2], -sv[3]),
                                      pk2(-sv[4], -sv[5]), pk2(-sv[6], -sv[7]));
                int lb = lg * 2 + h;          // l-block index within 64 (8 blocks)
                *(uint4*)(Bs + c0 * 64 + ((lb ^ (c0 & 7)) * 8)) = pc;
                *(uint4*)(Bs + c1 * 64 + ((lb ^ (c1 & 7)) * 8)) = ps;
            }
        }
        __syncthreads();
#pragma unroll
        for (int kst = 0; kst < 2; ++kst) {
            short8 af[2], bfr[4];
#pragma unroll
            for (int mt = 0; mt < 2; ++mt) {
                int m = wtm * 32 + mt * 16 + lid;
                int cb = (kst * 4 + quad) ^ (m & 7);
                af[mt] = *(short8*)(As + m * 64 + cb * 8);
            }
#pragma unroll
            for (int nt = 0; nt < 4; ++nt) {
                int n = wtn * 64 + nt * 16 + lid;
                int cb = (kst * 4 + quad) ^ (n & 7);
                bfr[nt] = *(short8*)(Bs + n * 64 + cb * 8);
            }
#pragma unroll
            for (int mt = 0; mt < 2; ++mt)
#pragma unroll
                for (int nt = 0; nt < 4; ++nt)
                    acc[mt][nt] = __builtin_amdgcn_mfma_f32_16x16x32_bf16(af[mt], bfr[nt], acc[mt][nt], 0, 0, 0);
        }
        __syncthreads();
    }
    // epilogue: C/D layout col=lane&15, row=quad*4+reg; bf16 scalar stores
    unsigned short* dst = C1P + (((size_t)ks * Bsz + b) * HEsz + he0) * 128;
#pragma unroll
    for (int mt = 0; mt < 2; ++mt)
#pragma unroll
        for (int nt = 0; nt < 4; ++nt)
#pragma unroll
            for (int r = 0; r < 4; ++r)
                dst[(size_t)(wtm * 32 + mt * 16 + quad * 4 + r) * 128 + wtn * 64 + nt * 16 + lid] =
                    f2bf(acc[mt][nt][r]);
}

// ---- Stage 2: fused split-K reduce + head mixing, bf16 Cf output ----
// grid (4b * 64e) = 256 blocks. Block reduces X[i=8][c=128] over SPLIT bf16 partials,
// then res[o,m] = sum_i X[i,m] * w[i,o,e,m]; Cf = (Re, -Im) bf16 (1/L weights folded
// into the inverse basis inside k_idft).
__global__ __launch_bounds__(256) void k_mixreduce(const unsigned short* __restrict__ C1P,
                                                   const float* __restrict__ wr,
                                                   const float* __restrict__ wi,
                                                   unsigned short* __restrict__ Cf) {
    __shared__ float X[8][128];
    const int e = blockIdx.x & 63, b = blockIdx.x >> 6;
    const int t = threadIdx.x;
    const int i = t >> 5, c4 = t & 31;        // 4 c's per thread
    size_t off = ((size_t)b * HEsz + i * 64 + e) * 128 + c4 * 4;
    float sx = 0.f, sy = 0.f, sz = 0.f, sw = 0.f;
    for (int sp = 0; sp < SPLIT; ++sp) {
        uint2 v = *(const uint2*)(C1P + off + (size_t)sp * (Bsz * HEsz * 128));
        sx += bf2f((unsigned short)(v.x & 0xffff));
        sy += bf2f((unsigned short)(v.x >> 16));
        sz += bf2f((unsigned short)(v.y & 0xffff));
        sw += bf2f((unsigned short)(v.y >> 16));
    }
    *(float4*)&X[i][c4 * 4] = make_float4(sx, sy, sz, sw);
    __syncthreads();
#pragma unroll
    for (int it = 0; it < 2; ++it) {
        int item = t + it * 256;              // 512: o = item>>6, m = item&63
        int o = item >> 6, m = item & 63;
        float ar = 0.f, ai = 0.f;
#pragma unroll
        for (int i2 = 0; i2 < 8; ++i2) {
            float xr = X[i2][2 * m], xi = X[i2][2 * m + 1];
            size_t wo = ((size_t)(i2 * 8 + o) * 64 + e) * 64 + m;
            float wrv = wr[wo], wiv = wi[wo];
            ar += xr * wrv - xi * wiv;
            ai += xr * wiv + xi * wrv;
        }
        int row = b * HEsz + o * 64 + e;
        *(unsigned*)(Cf + (size_t)row * 128 + 2 * m) = pk2(ar, -ai);
    }
}

// ---- Stage 3: truncated irfft, bf16 MFMA, inverse basis generated in-kernel ----
// out[row][l] = sum_k Cf[row][k] * basI[k][l]; basI[2m][l]=wm*cos, [2m+1][l]=wm*sin,
// wm = (m==0?1:2)/L. grid (32 lt, 16 rt), tile 128x128, K=128.
__global__ __launch_bounds__(256, 2) void k_idft(const unsigned short* __restrict__ Cf,
                                                 float* __restrict__ out) {
    __shared__ unsigned short As[128 * 128];  // [row][k] swz16, 32 KB
    __shared__ unsigned short Bs[128 * 128];  // [l][k]  swz16, 32 KB
    const int l0 = blockIdx.x * 128, row0 = blockIdx.y * 128;
    const int t = threadIdx.x, lane = t & 63, w = t >> 6;
    const int wtm = w & 1, wtn = w >> 1;      // wave tile 64 x 64
    const int quad = lane >> 4, lid = lane & 15;
    // A: stage Cf rows
#pragma unroll
    for (int it = 0; it < 8; ++it) {
        int slot = t + it * 256;              // 2048: r = slot>>4, cb = slot&15
        int r = slot >> 4, cb = slot & 15;
        uint4 a = *(const uint4*)(Cf + (size_t)(row0 + r) * 128 + cb * 8);
        *(uint4*)(As + r * 128 + ((cb ^ (r & 15)) * 8)) = a;
    }
    // B: generate basI tile. thread -> l-row = t>>1, half = t&1 (32 m's each).
    {
        int lr = t >> 1, half = t & 1;
        int lg = l0 + lr;
#pragma unroll
        for (int jj = 0; jj < 8; ++jj) {      // 8 k-blocks of 8 (= 4 m's each)
            unsigned wv[4];
#pragma unroll
            for (int j = 0; j < 4; ++j) {
                int m = half * 32 + jj * 4 + j;
                float s, co; sc(m, lg, &s, &co);
                float wm = (m == 0) ? (1.0f / Lsz) : (2.0f / Lsz);
                wv[j] = pk2(wm * co, wm * s);
            }
            int cb = half * 8 + jj;
            *(uint4*)(Bs + lr * 128 + ((cb ^ (lr & 15)) * 8)) =
                make_uint4(wv[0], wv[1], wv[2], wv[3]);
        }
    }
    __syncthreads();
    f32x4 acc[4][4] = {};
#pragma unroll
    for (int kst = 0; kst < 4; ++kst) {
        short8 af[4], bfr[4];
#pragma unroll
        for (int mt = 0; mt < 4; ++mt) {
            int m = wtm * 64 + mt * 16 + lid;
            int cb = (kst * 4 + quad) ^ (m & 15);
            af[mt] = *(short8*)(As + m * 128 + cb * 8);
        }
#pragma unroll
        for (int nt = 0; nt < 4; ++nt) {
            int n = wtn * 64 + nt * 16 + lid;
            int cb = (kst * 4 + quad) ^ (n & 15);
            bfr[nt] = *(short8*)(Bs + n * 128 + cb * 8);
        }
#pragma unroll
        for (int mt = 0; mt < 4; ++mt)
#pragma unroll
            for (int nt = 0; nt < 4; ++nt)
                acc[mt][nt] = __builtin_amdgcn_mfma_f32_16x16x32_bf16(af[mt], bfr[nt], acc[mt][nt], 0, 0, 0);
    }
    __syncthreads();
    // transpose through LDS (reuse As/Bs as float[128][128]) for float4 stores
    float* outb = (float*)As;
#pragma unroll
    for (int mt = 0; mt < 4; ++mt)
#pragma unroll
        for (int nt = 0; nt < 4; ++nt)
#pragma unroll
            for (int r = 0; r < 4; ++r)
                outb[(size_t)(wtm * 64 + mt * 16 + quad * 4 + r) * 128 + wtn * 64 + nt * 16 + lid] =
                    acc[mt][nt][r];
    __syncthreads();
#pragma unroll
    for (int it = 0; it < 16; ++it) {
        int slot = t + it * 256;              // 4096 float4: r = slot>>5, c4 = slot&31
        int r = slot >> 5, c4 = slot & 31;
        float4 v = *(float4*)(outb + (size_t)r * 128 + c4 * 4);
        *(float4*)(out + (size_t)(row0 + r) * Lsz + l0 + c4 * 4) = v;
    }
}

extern "C" void kernel_launch(void* const* d_in, const int* in_sizes, int n_in,
                              void* d_out, int out_size, void* d_ws, size_t ws_size,
                              hipStream_t stream) {
    const float* q      = (const float*)d_in[0];
    const float* w_real = (const float*)d_in[3];
    const float* w_imag = (const float*)d_in[4];
    float* out = (float*)d_out;
    char* ws = (char*)d_ws;                   // needs ~9 MiB

    unsigned short* Cf  = (unsigned short*)(ws + OFF_CF);
    unsigned short* C1P = (unsigned short*)(ws + OFF_C1P);

    k_dft      <<<dim3(SPLIT, 8, 4), 256, 0, stream>>>(q, C1P);
    k_mixreduce<<<256, 256, 0, stream>>>(C1P, w_real, w_imag, Cf);
    k_idft     <<<dim3(32, 16), 256, 0, stream>>>(Cf, out);
}